// Round 1
// baseline (5722.865 us; speedup 1.0000x reference)
//
#include <hip/hip_runtime.h>
#include <math.h>

// Problem constants
#define BB 8
#define NN 16384      // H*W = 128*128
#define CCH 256       // input channels
#define OCH 512       // conv output channels = INNER
#define IMG 128

typedef float4 f4;

__device__ __forceinline__ f4 ldg4(const float* p) { return *(const f4*)p; }

// ---------------------------------------------------------------------------
// Kernel W: re-layout conv weights (O,I,3,3) -> Wt[tap][c][o] so conv B-tiles
// load coalesced (consecutive o contiguous).
// ---------------------------------------------------------------------------
__global__ __launch_bounds__(256) void wtrans(const float* __restrict__ cw,
                                              float* __restrict__ Wt) {
  int tid = blockIdx.x * 256 + threadIdx.x;   // 9*256*512 = 1179648 exact
  int o = tid & 511;
  int rest = tid >> 9;
  int c = rest & 255;
  int t = rest >> 8;
  Wt[tid] = cw[o * 2304 + c * 9 + t];
}

// ---------------------------------------------------------------------------
// Kernel A: 3x3 SAME conv as implicit GEMM.
// Tile: 128 pixels (one image row) x 128 out-channels, 256 threads, 8x8 micro.
// K = 9 taps * 256 ch, chunked by 16. Output xc[b][n][o] (B,N,512).
// ---------------------------------------------------------------------------
__global__ __launch_bounds__(256) void conv_gemm(const float* __restrict__ x,
                                                 const float* __restrict__ Wt,
                                                 const float* __restrict__ cb,
                                                 float* __restrict__ xc) {
  __shared__ float As[16 * 132];   // [k][m] +4 pad
  __shared__ float Bs[16 * 132];   // [k][o] +4 pad
  const int t = threadIdx.x;
  const int tx = t & 15, ty = t >> 4;
  const int obase = blockIdx.x * 128;          // 4 o-tiles
  const int bi = blockIdx.y >> 7;              // batch
  const int yy = blockIdx.y & 127;             // image row
  float acc[8][8];
#pragma unroll
  for (int i = 0; i < 8; ++i)
#pragma unroll
    for (int j = 0; j < 8; ++j) acc[i][j] = 0.f;

  const int lc4 = (t & 3) * 4;   // A-load channel offset within chunk
  const int lm = t >> 2;         // A-load pixel 0..63
  const int lo4 = (t & 31) * 4;  // B-load o offset
  const int lcb = t >> 5;        // B-load c row 0..7

  for (int tap = 0; tap < 9; ++tap) {
    const int dy = tap / 3 - 1, dx = tap % 3 - 1;
    const int ysrc = yy + dy;
    const bool yok = (unsigned)ysrc < 128u;
    const float* xb = x + ((size_t)bi * NN + (size_t)ysrc * IMG) * CCH;
    const float* wb = Wt + (size_t)tap * 256 * 512 + obase;
    for (int cc = 0; cc < 16; ++cc) {
      __syncthreads();
      // stage A (transposed [c][m]) with SAME-padding bounds
#pragma unroll
      for (int p = 0; p < 2; ++p) {
        int m = lm + p * 64;
        int xs_ = m + dx;
        f4 av = make_float4(0.f, 0.f, 0.f, 0.f);
        if (yok && (unsigned)xs_ < 128u)
          av = ldg4(xb + (size_t)xs_ * CCH + cc * 16 + lc4);
        As[(lc4 + 0) * 132 + m] = av.x;
        As[(lc4 + 1) * 132 + m] = av.y;
        As[(lc4 + 2) * 132 + m] = av.z;
        As[(lc4 + 3) * 132 + m] = av.w;
      }
      // stage B ([c][o], already o-contiguous in Wt)
#pragma unroll
      for (int p = 0; p < 2; ++p) {
        int c = lcb + p * 8;
        f4 bv = ldg4(wb + (size_t)(cc * 16 + c) * 512 + lo4);
        *(f4*)&Bs[c * 132 + lo4] = bv;
      }
      __syncthreads();
      const f4* As4 = (const f4*)As;
      const f4* Bs4 = (const f4*)Bs;
#pragma unroll
      for (int k = 0; k < 16; ++k) {
        f4 a0 = As4[k * 33 + ty * 2];
        f4 a1 = As4[k * 33 + ty * 2 + 1];
        f4 b0 = Bs4[k * 33 + tx * 2];
        f4 b1 = Bs4[k * 33 + tx * 2 + 1];
        float a[8] = {a0.x, a0.y, a0.z, a0.w, a1.x, a1.y, a1.z, a1.w};
        float b[8] = {b0.x, b0.y, b0.z, b0.w, b1.x, b1.y, b1.z, b1.w};
#pragma unroll
        for (int i = 0; i < 8; ++i)
#pragma unroll
          for (int j = 0; j < 8; ++j) acc[i][j] = fmaf(a[i], b[j], acc[i][j]);
      }
    }
  }
  float bcol[8];
#pragma unroll
  for (int j = 0; j < 8; ++j) bcol[j] = cb[obase + tx * 8 + j];
#pragma unroll
  for (int i = 0; i < 8; ++i) {
    int m = ty * 8 + i;
    size_t base = ((size_t)bi * NN + (size_t)yy * IMG + m) * OCH + obase + tx * 8;
    *(f4*)&xc[base] = make_float4(acc[i][0] + bcol[0], acc[i][1] + bcol[1],
                                  acc[i][2] + bcol[2], acc[i][3] + bcol[3]);
    *(f4*)&xc[base + 4] = make_float4(acc[i][4] + bcol[4], acc[i][5] + bcol[5],
                                      acc[i][6] + bcol[6], acc[i][7] + bcol[7]);
  }
}

// ---------------------------------------------------------------------------
// Kernel B: fused K/V projection + kv accumulation (never materializes K,V).
// Per (b,h,split): each wave streams rows; lane c holds klog[c], v[c];
// macc[d] (64 VGPRs) accumulates M[d][c] = sum_n exp(klog[d]) * v[c];
// ssum accumulates S[c] = sum_n exp(klog[c]). Writes split partials (no atomics).
// ---------------------------------------------------------------------------
__global__ __launch_bounds__(256) void bkern(const float* __restrict__ xc,
                                             const float* __restrict__ Wk,
                                             const float* __restrict__ Wv,
                                             float* __restrict__ P,
                                             float* __restrict__ PS) {
  __shared__ float wkT[4096];      // [d][c] = Wk[c][d]
  __shared__ float wvT[4096];
  __shared__ float red[64 * 65];   // block reduce, +1 pad
  __shared__ float Sred[64];
  const int t = threadIdx.x;
  const int bh = blockIdx.x >> 3;
  const int sp = blockIdx.x & 7;
  const int b = bh >> 3, h = bh & 7;
  {
    int d4 = (t & 15) * 4;
#pragma unroll
    for (int p = 0; p < 4; ++p) {
      int kr = (t >> 4) + p * 16;
      f4 wk = ldg4(Wk + kr * 64 + d4);
      f4 wv = ldg4(Wv + kr * 64 + d4);
      wkT[(d4 + 0) * 64 + kr] = wk.x; wkT[(d4 + 1) * 64 + kr] = wk.y;
      wkT[(d4 + 2) * 64 + kr] = wk.z; wkT[(d4 + 3) * 64 + kr] = wk.w;
      wvT[(d4 + 0) * 64 + kr] = wv.x; wvT[(d4 + 1) * 64 + kr] = wv.y;
      wvT[(d4 + 2) * 64 + kr] = wv.z; wvT[(d4 + 3) * 64 + kr] = wv.w;
    }
  }
  __syncthreads();
  const int lane = t & 63, w = t >> 6;
  float macc[64];
#pragma unroll
  for (int d = 0; d < 64; ++d) macc[d] = 0.f;
  float ssum = 0.f;
  const int nbase = sp * 2048 + w * 512;
  const float* xrow = xc + (size_t)(b * NN + nbase) * OCH + h * 64 + lane;
  for (int r = 0; r < 512; ++r) {
    float xv = *xrow;
    xrow += OCH;
    int xi = __float_as_int(xv);
    float klog = 0.f, vv = 0.f;
#pragma unroll
    for (int d = 0; d < 64; ++d) {
      float xd = __int_as_float(__builtin_amdgcn_readlane(xi, d));
      klog = fmaf(xd, wkT[d * 64 + lane], klog);
      vv = fmaf(xd, wvT[d * 64 + lane], vv);
    }
    float ek = expf(klog);
    ssum += ek;
    int ei = __float_as_int(ek);
#pragma unroll
    for (int d = 0; d < 64; ++d) {
      float ekd = __int_as_float(__builtin_amdgcn_readlane(ei, d));
      macc[d] = fmaf(ekd, vv, macc[d]);
    }
  }
  // reduce 4 waves -> red/Sred
  for (int ww = 0; ww < 4; ++ww) {
    if (w == ww) {
      if (ww == 0) {
#pragma unroll
        for (int d = 0; d < 64; ++d) red[d * 65 + lane] = macc[d];
        Sred[lane] = ssum;
      } else {
#pragma unroll
        for (int d = 0; d < 64; ++d) red[d * 65 + lane] += macc[d];
        Sred[lane] += ssum;
      }
    }
    __syncthreads();
  }
  float* Pp = P + (size_t)blockIdx.x * 4096;
#pragma unroll
  for (int e = 0; e < 16; ++e) {
    int idx = t + e * 256;
    Pp[idx] = red[(idx >> 6) * 65 + (idx & 63)];
  }
  if (t < 64) PS[blockIdx.x * 64 + t] = Sred[t];
}

// ---------------------------------------------------------------------------
// Kernel C: kv[bh][d][c] = sum_sp P / sum_sp S[d]
// ---------------------------------------------------------------------------
__global__ __launch_bounds__(256) void ckern(const float* __restrict__ P,
                                             const float* __restrict__ PS,
                                             float* __restrict__ kvb) {
  int bh = blockIdx.x, t = threadIdx.x;
#pragma unroll
  for (int e = 0; e < 16; ++e) {
    int idx = t + e * 256;
    int d = idx >> 6;
    float m = 0.f, s = 0.f;
    for (int sp = 0; sp < 8; ++sp) {
      m += P[(size_t)(bh * 8 + sp) * 4096 + idx];
      s += PS[(bh * 8 + sp) * 64 + d];
    }
    kvb[(size_t)bh * 4096 + idx] = m / s;
  }
}

// ---------------------------------------------------------------------------
// Kernel D1: per 64-row tile, per head: qlog = X@WqT, softmax over kr,
// qkv = softmax(q) @ kv  -- written IN-PLACE over xc rows.
// ---------------------------------------------------------------------------
__global__ __launch_bounds__(256) void d1kern(float* __restrict__ xc,
                                              const float* __restrict__ Wq,
                                              const float* __restrict__ kvb) {
  __shared__ float WqT[64 * 68];  // [d][kr]
  __shared__ float kvs[64 * 68];  // [kr][c]
  __shared__ float Xs[64 * 68];   // [d][row]
  __shared__ float Et[64 * 68];   // [kr][row]
  __shared__ float rs[64];
  const int t = threadIdx.x;
  const int tx = t & 15, ty = t >> 4;
  const int row0 = blockIdx.x * 64;
  const int b = row0 >> 14;
  {
    int d4 = (t & 15) * 4;
#pragma unroll
    for (int p = 0; p < 4; ++p) {
      int kr = (t >> 4) + p * 16;
      f4 wq = ldg4(Wq + kr * 64 + d4);
      WqT[(d4 + 0) * 68 + kr] = wq.x; WqT[(d4 + 1) * 68 + kr] = wq.y;
      WqT[(d4 + 2) * 68 + kr] = wq.z; WqT[(d4 + 3) * 68 + kr] = wq.w;
    }
  }
  for (int h = 0; h < 8; ++h) {
    __syncthreads();
    // stage kv[b,h]
#pragma unroll
    for (int p = 0; p < 4; ++p) {
      int lin4 = t + p * 256;
      int d = lin4 >> 4;
      int c = (lin4 & 15) * 4;
      f4 kv = ldg4(kvb + (size_t)(b * 8 + h) * 4096 + lin4 * 4);
      *(f4*)&kvs[d * 68 + c] = kv;
    }
    // stage X chunk transposed
    {
      int d4 = (t & 15) * 4;
#pragma unroll
      for (int p = 0; p < 4; ++p) {
        int r = (t >> 4) + p * 16;
        f4 xv = ldg4(xc + (size_t)(row0 + r) * OCH + h * 64 + d4);
        Xs[(d4 + 0) * 68 + r] = xv.x; Xs[(d4 + 1) * 68 + r] = xv.y;
        Xs[(d4 + 2) * 68 + r] = xv.z; Xs[(d4 + 3) * 68 + r] = xv.w;
      }
    }
    __syncthreads();
    // GEMM1: qlog[row][kr]
    float a1[4][4];
#pragma unroll
    for (int i = 0; i < 4; ++i)
#pragma unroll
      for (int j = 0; j < 4; ++j) a1[i][j] = 0.f;
    const f4* Xs4 = (const f4*)Xs;
    const f4* Wq4 = (const f4*)WqT;
#pragma unroll 8
    for (int k = 0; k < 64; ++k) {
      f4 a = Xs4[k * 17 + ty];
      f4 bq = Wq4[k * 17 + tx];
      float av[4] = {a.x, a.y, a.z, a.w};
      float bv[4] = {bq.x, bq.y, bq.z, bq.w};
#pragma unroll
      for (int i = 0; i < 4; ++i)
#pragma unroll
        for (int j = 0; j < 4; ++j) a1[i][j] = fmaf(av[i], bv[j], a1[i][j]);
    }
#pragma unroll
    for (int i = 0; i < 4; ++i)
#pragma unroll
      for (int j = 0; j < 4; ++j)
        Et[(tx * 4 + j) * 68 + ty * 4 + i] = expf(a1[i][j]);
    __syncthreads();
    if (t < 64) {
      float s = 0.f;
      for (int kr = 0; kr < 64; ++kr) s += Et[kr * 68 + t];
      rs[t] = s;
    }
    __syncthreads();
    // GEMM2: qkv[row][c] = (E @ kv) / rowsum
    float a2[4][4];
#pragma unroll
    for (int i = 0; i < 4; ++i)
#pragma unroll
      for (int j = 0; j < 4; ++j) a2[i][j] = 0.f;
    const f4* Et4 = (const f4*)Et;
    const f4* kv4 = (const f4*)kvs;
#pragma unroll 8
    for (int k = 0; k < 64; ++k) {
      f4 a = Et4[k * 17 + ty];
      f4 bv = kv4[k * 17 + tx];
      float av[4] = {a.x, a.y, a.z, a.w};
      float bb[4] = {bv.x, bv.y, bv.z, bv.w};
#pragma unroll
      for (int i = 0; i < 4; ++i)
#pragma unroll
        for (int j = 0; j < 4; ++j) a2[i][j] = fmaf(av[i], bb[j], a2[i][j]);
    }
#pragma unroll
    for (int i = 0; i < 4; ++i) {
      float inv = 1.0f / rs[ty * 4 + i];
      *(f4*)&xc[(size_t)(row0 + ty * 4 + i) * OCH + h * 64 + tx * 4] =
          make_float4(a2[i][0] * inv, a2[i][1] * inv, a2[i][2] * inv, a2[i][3] * inv);
    }
  }
}

// ---------------------------------------------------------------------------
// Kernel mlp<K,GELU>: Y(row,j) = act(X(row,:) @ W[j,:] + bias[j])
// Tile 128 rows x 128 j, 8x8 micro, K chunked by 64. Output stride 256.
// ---------------------------------------------------------------------------
template <int KTOT, bool DOGELU>
__global__ __launch_bounds__(256) void mlp(const float* __restrict__ X,
                                           const float* __restrict__ W,
                                           const float* __restrict__ bias,
                                           float* __restrict__ Y) {
  __shared__ float Xs[64 * 132];  // [k][row]
  __shared__ float Ws[64 * 132];  // [k][j]
  const int t = threadIdx.x;
  const int tx = t & 15, ty = t >> 4;
  const int jbase = blockIdx.x * 128;
  const int row0 = blockIdx.y * 128;
  float acc[8][8];
#pragma unroll
  for (int i = 0; i < 8; ++i)
#pragma unroll
    for (int j = 0; j < 8; ++j) acc[i][j] = 0.f;
  const int d4 = (t & 15) * 4;
  for (int kc = 0; kc < KTOT / 64; ++kc) {
    int kb = kc * 64;
    __syncthreads();
#pragma unroll
    for (int p = 0; p < 8; ++p) {
      int r = (t >> 4) + p * 16;
      f4 xv = ldg4(X + (size_t)(row0 + r) * KTOT + kb + d4);
      Xs[(d4 + 0) * 132 + r] = xv.x; Xs[(d4 + 1) * 132 + r] = xv.y;
      Xs[(d4 + 2) * 132 + r] = xv.z; Xs[(d4 + 3) * 132 + r] = xv.w;
    }
#pragma unroll
    for (int p = 0; p < 8; ++p) {
      int jj = (t >> 4) + p * 16;
      f4 wv = ldg4(W + (size_t)(jbase + jj) * KTOT + kb + d4);
      Ws[(d4 + 0) * 132 + jj] = wv.x; Ws[(d4 + 1) * 132 + jj] = wv.y;
      Ws[(d4 + 2) * 132 + jj] = wv.z; Ws[(d4 + 3) * 132 + jj] = wv.w;
    }
    __syncthreads();
    const f4* Xs4 = (const f4*)Xs;
    const f4* Ws4 = (const f4*)Ws;
#pragma unroll 8
    for (int k = 0; k < 64; ++k) {
      f4 a0 = Xs4[k * 33 + ty * 2];
      f4 a1 = Xs4[k * 33 + ty * 2 + 1];
      f4 b0 = Ws4[k * 33 + tx * 2];
      f4 b1 = Ws4[k * 33 + tx * 2 + 1];
      float a[8] = {a0.x, a0.y, a0.z, a0.w, a1.x, a1.y, a1.z, a1.w};
      float b[8] = {b0.x, b0.y, b0.z, b0.w, b1.x, b1.y, b1.z, b1.w};
#pragma unroll
      for (int i = 0; i < 8; ++i)
#pragma unroll
        for (int j = 0; j < 8; ++j) acc[i][j] = fmaf(a[i], b[j], acc[i][j]);
    }
  }
  float bb[8];
#pragma unroll
  for (int j = 0; j < 8; ++j) bb[j] = bias[jbase + tx * 8 + j];
#pragma unroll
  for (int i = 0; i < 8; ++i) {
    int row = row0 + ty * 8 + i;
    float v[8];
#pragma unroll
    for (int j = 0; j < 8; ++j) {
      v[j] = acc[i][j] + bb[j];
      if (DOGELU) v[j] = 0.5f * v[j] * (1.0f + erff(v[j] * 0.70710678118654752440f));
    }
    *(f4*)&Y[(size_t)row * 256 + jbase + tx * 8] = make_float4(v[0], v[1], v[2], v[3]);
    *(f4*)&Y[(size_t)row * 256 + jbase + tx * 8 + 4] = make_float4(v[4], v[5], v[6], v[7]);
  }
}

// ---------------------------------------------------------------------------
extern "C" void kernel_launch(void* const* d_in, const int* in_sizes, int n_in,
                              void* d_out, int out_size, void* d_ws, size_t ws_size,
                              hipStream_t stream) {
  const float* x  = (const float*)d_in[0];
  const float* cw = (const float*)d_in[1];
  const float* cb = (const float*)d_in[2];
  const float* Wq = (const float*)d_in[3];
  const float* Wk = (const float*)d_in[4];
  const float* Wv = (const float*)d_in[5];
  const float* W1 = (const float*)d_in[6];
  const float* b1 = (const float*)d_in[7];
  const float* W2 = (const float*)d_in[8];
  const float* b2 = (const float*)d_in[9];
  float* out = (float*)d_out;
  float* ws = (float*)d_ws;

  float* xc  = ws;                  // 67,108,864 floats (B,N,512)
  float* Wt  = xc + 67108864;       // 1,179,648   (9,256,512)
  float* P   = Wt + 1179648;        // 2,097,152   (64 bh * 8 splits * 4096)
  float* PS  = P + 2097152;         // 32,768
  float* kvb = PS + 32768;          // 262,144     (64 bh * 64 * 64)
  float* y1w = kvb + 262144;        // 33,554,432  (B,N,256)

  wtrans<<<4608, 256, 0, stream>>>(cw, Wt);
  conv_gemm<<<dim3(4, 1024), 256, 0, stream>>>(x, Wt, cb, xc);
  bkern<<<512, 256, 0, stream>>>(xc, Wk, Wv, P, PS);
  ckern<<<64, 256, 0, stream>>>(P, PS, kvb);
  d1kern<<<2048, 256, 0, stream>>>(xc, Wq, kvb);
  mlp<512, true><<<dim3(2, 1024), 256, 0, stream>>>(xc, W1, b1, y1w);
  mlp<256, false><<<dim3(2, 1024), 256, 0, stream>>>(y1w, W2, b2, out);
}

// Round 2
// 3495.535 us; speedup vs baseline: 1.6372x; 1.6372x over previous
//
#include <hip/hip_runtime.h>
#include <math.h>

// Problem constants
#define BB 8
#define NN 16384      // H*W = 128*128
#define CCH 256       // input channels
#define OCH 512       // conv output channels = INNER
#define IMG 128

typedef float4 f4;
typedef _Float16 half8 __attribute__((ext_vector_type(8)));
typedef float floatx4 __attribute__((ext_vector_type(4)));

__device__ __forceinline__ f4 ldg4(const float* p) { return *(const f4*)p; }

// async global->LDS, 16B per lane; LDS dest = wave-uniform base + lane*16
__device__ __forceinline__ void gl16(const _Float16* g, const _Float16* l) {
  __builtin_amdgcn_global_load_lds(
      (const __attribute__((address_space(1))) void*)g,
      (__attribute__((address_space(3))) void*)l, 16, 0, 0);
}

// ---------------------------------------------------------------------------
// pad_split: x fp32 [8][128][128][256] -> zero-haloed fp16 hi/lo [8][130][130][256]
// hi = f16(x), lo = f16(x - hi). Halo rows/cols written as zeros every call.
// ---------------------------------------------------------------------------
__global__ __launch_bounds__(256) void pad_split(const float* __restrict__ x,
                                                 _Float16* __restrict__ xh,
                                                 _Float16* __restrict__ xl) {
  int tid = blockIdx.x * 256 + threadIdx.x;   // 8*130*130*32 = 4,326,400 exact
  int c8 = tid & 31;
  int p = tid >> 5;
  int xcol = p % 130;
  int p2 = p / 130;
  int y = p2 % 130;
  int b = p2 / 130;
  half8 hv, lv;
#pragma unroll
  for (int j = 0; j < 8; ++j) { hv[j] = (_Float16)0.f; lv[j] = (_Float16)0.f; }
  if (y >= 1 && y <= 128 && xcol >= 1 && xcol <= 128) {
    const float* src = x + ((size_t)(b * 128 + y - 1) * 128 + (xcol - 1)) * 256 + c8 * 8;
    f4 v0 = ldg4(src);
    f4 v1 = ldg4(src + 4);
    float vv[8] = {v0.x, v0.y, v0.z, v0.w, v1.x, v1.y, v1.z, v1.w};
#pragma unroll
    for (int j = 0; j < 8; ++j) {
      _Float16 h = (_Float16)vv[j];
      hv[j] = h;
      lv[j] = (_Float16)(vv[j] - (float)h);
    }
  }
  size_t dst = (size_t)p * 256 + c8 * 8;
  *(half8*)(xh + dst) = hv;
  *(half8*)(xl + dst) = lv;
}

// ---------------------------------------------------------------------------
// wsplit: conv_w fp32 [512][256][3][3] -> fp16 hi/lo Bt[tap][o][c] (o-major rows)
// ---------------------------------------------------------------------------
__global__ __launch_bounds__(256) void wsplit(const float* __restrict__ cw,
                                              _Float16* __restrict__ wh,
                                              _Float16* __restrict__ wl) {
  int tid = blockIdx.x * 256 + threadIdx.x;   // 9*512*32 = 147,456 exact
  int c8 = tid & 31;
  int o = (tid >> 5) & 511;
  int tap = tid >> 14;
  half8 hv, lv;
#pragma unroll
  for (int j = 0; j < 8; ++j) {
    float v = cw[(size_t)o * 2304 + (c8 * 8 + j) * 9 + tap];
    _Float16 h = (_Float16)v;
    hv[j] = h;
    lv[j] = (_Float16)(v - (float)h);
  }
  size_t dst = ((size_t)tap * 512 + o) * 256 + c8 * 8;
  *(half8*)(wh + dst) = hv;
  *(half8*)(wl + dst) = lv;
}

// ---------------------------------------------------------------------------
// conv_mfma: 3x3 SAME conv as implicit GEMM via fp16x2-split MFMA.
// Block: 128 pixels (one image row) x 128 outch. 4 waves, each 64x64 (4x4 tiles
// of 16x16x32). K = 9 taps x 256 ch, BK=32. LDS [k8][idx] 16B-blocked layout,
// staged with global_load_lds (conflict-free both directions).
// 3 MFMA terms per tile: ah*bh + al*bh + ah*bl (lo*lo dropped, ~2^-22 rel).
// ---------------------------------------------------------------------------
__global__ __launch_bounds__(256) void conv_mfma(const _Float16* __restrict__ xph,
                                                 const _Float16* __restrict__ xpl,
                                                 const _Float16* __restrict__ wh,
                                                 const _Float16* __restrict__ wl,
                                                 const float* __restrict__ cb,
                                                 float* __restrict__ xc) {
  __shared__ __align__(16) _Float16 sm[16384];  // 32KB: AH@0 AL@4096 BH@8192 BL@12288
  const int t = threadIdx.x;
  const int w = t >> 6, lane = t & 63;
  const int obase = blockIdx.x * 128;
  const int bi = blockIdx.y >> 7, yy = blockIdx.y & 127;
  const int wm = (w & 1) * 64, wn = (w >> 1) * 64;

  floatx4 acc[4][4];
#pragma unroll
  for (int i = 0; i < 4; ++i)
#pragma unroll
    for (int j = 0; j < 4; ++j) acc[i][j] = (floatx4){0.f, 0.f, 0.f, 0.f};

  // staging groups: wave w handles slot-groups g0=w, g1=4+w (64 slots of 16B each)
  const int g0 = w, g1 = 4 + w;
  const int k8_0 = g0 >> 1, id0 = (g0 & 1) * 64 + lane;
  const int k8_1 = g1 >> 1, id1 = (g1 & 1) * 64 + lane;

  for (int tap = 0; tap < 9; ++tap) {
    const int dy = tap / 3, dx = tap % 3;   // padded offsets: y=yy+dy, col=m+dx
    const _Float16* ah_src = xph + ((size_t)(bi * 130 + yy + dy) * 130 + dx) * 256;
    const _Float16* al_src = xpl + ((size_t)(bi * 130 + yy + dy) * 130 + dx) * 256;
    const _Float16* bh_src = wh + ((size_t)tap * 512 + obase) * 256;
    const _Float16* bl_src = wl + ((size_t)tap * 512 + obase) * 256;
    for (int cc = 0; cc < 8; ++cc) {
      const int c0 = cc * 32;
      const size_t off0 = (size_t)id0 * 256 + c0 + k8_0 * 8;
      const size_t off1 = (size_t)id1 * 256 + c0 + k8_1 * 8;
      __syncthreads();
      gl16(ah_src + off0, &sm[g0 * 512]);
      gl16(ah_src + off1, &sm[g1 * 512]);
      gl16(al_src + off0, &sm[4096 + g0 * 512]);
      gl16(al_src + off1, &sm[4096 + g1 * 512]);
      gl16(bh_src + off0, &sm[8192 + g0 * 512]);
      gl16(bh_src + off1, &sm[8192 + g1 * 512]);
      gl16(bl_src + off0, &sm[12288 + g0 * 512]);
      gl16(bl_src + off1, &sm[12288 + g1 * 512]);
      __syncthreads();

      const int kq = (lane >> 4) * 1024;      // k8 * 128 * 8 halfs
      const int ar = (wm + (lane & 15)) * 8;
      const int br = (wn + (lane & 15)) * 8;
      half8 ah[4], al[4], bh[4], bl[4];
#pragma unroll
      for (int mt = 0; mt < 4; ++mt) {
        ah[mt] = *(const half8*)&sm[kq + ar + mt * 128];
        al[mt] = *(const half8*)&sm[4096 + kq + ar + mt * 128];
      }
#pragma unroll
      for (int nt = 0; nt < 4; ++nt) {
        bh[nt] = *(const half8*)&sm[8192 + kq + br + nt * 128];
        bl[nt] = *(const half8*)&sm[12288 + kq + br + nt * 128];
      }
#pragma unroll
      for (int mt = 0; mt < 4; ++mt)
#pragma unroll
        for (int nt = 0; nt < 4; ++nt) {
          acc[mt][nt] = __builtin_amdgcn_mfma_f32_16x16x32_f16(ah[mt], bh[nt], acc[mt][nt], 0, 0, 0);
          acc[mt][nt] = __builtin_amdgcn_mfma_f32_16x16x32_f16(al[mt], bh[nt], acc[mt][nt], 0, 0, 0);
          acc[mt][nt] = __builtin_amdgcn_mfma_f32_16x16x32_f16(ah[mt], bl[nt], acc[mt][nt], 0, 0, 0);
        }
    }
  }

  // epilogue: C/D layout col=lane&15, row=(lane>>4)*4+reg
  const int col = lane & 15;
  const int qr = (lane >> 4) * 4;
#pragma unroll
  for (int nt = 0; nt < 4; ++nt) {
    const int och = obase + wn + nt * 16 + col;
    const float bias = cb[och];
#pragma unroll
    for (int mt = 0; mt < 4; ++mt)
#pragma unroll
      for (int r = 0; r < 4; ++r) {
        int m = wm + mt * 16 + qr + r;
        xc[((size_t)bi * NN + (size_t)yy * IMG + m) * OCH + och] = acc[mt][nt][r] + bias;
      }
  }
}

// ---------------------------------------------------------------------------
// Kernel B: fused K/V projection + kv accumulation (never materializes K,V).
// ---------------------------------------------------------------------------
__global__ __launch_bounds__(256) void bkern(const float* __restrict__ xc,
                                             const float* __restrict__ Wk,
                                             const float* __restrict__ Wv,
                                             float* __restrict__ P,
                                             float* __restrict__ PS) {
  __shared__ float wkT[4096];      // [d][c] = Wk[c][d]
  __shared__ float wvT[4096];
  __shared__ float red[64 * 65];   // block reduce, +1 pad
  __shared__ float Sred[64];
  const int t = threadIdx.x;
  const int bh = blockIdx.x >> 3;
  const int sp = blockIdx.x & 7;
  const int b = bh >> 3, h = bh & 7;
  {
    int d4 = (t & 15) * 4;
#pragma unroll
    for (int p = 0; p < 4; ++p) {
      int kr = (t >> 4) + p * 16;
      f4 wk = ldg4(Wk + kr * 64 + d4);
      f4 wv = ldg4(Wv + kr * 64 + d4);
      wkT[(d4 + 0) * 64 + kr] = wk.x; wkT[(d4 + 1) * 64 + kr] = wk.y;
      wkT[(d4 + 2) * 64 + kr] = wk.z; wkT[(d4 + 3) * 64 + kr] = wk.w;
      wvT[(d4 + 0) * 64 + kr] = wv.x; wvT[(d4 + 1) * 64 + kr] = wv.y;
      wvT[(d4 + 2) * 64 + kr] = wv.z; wvT[(d4 + 3) * 64 + kr] = wv.w;
    }
  }
  __syncthreads();
  const int lane = t & 63, w = t >> 6;
  float macc[64];
#pragma unroll
  for (int d = 0; d < 64; ++d) macc[d] = 0.f;
  float ssum = 0.f;
  const int nbase = sp * 2048 + w * 512;
  const float* xrow = xc + (size_t)(b * NN + nbase) * OCH + h * 64 + lane;
  for (int r = 0; r < 512; ++r) {
    float xv = *xrow;
    xrow += OCH;
    int xi = __float_as_int(xv);
    float klog = 0.f, vv = 0.f;
#pragma unroll
    for (int d = 0; d < 64; ++d) {
      float xd = __int_as_float(__builtin_amdgcn_readlane(xi, d));
      klog = fmaf(xd, wkT[d * 64 + lane], klog);
      vv = fmaf(xd, wvT[d * 64 + lane], vv);
    }
    float ek = expf(klog);
    ssum += ek;
    int ei = __float_as_int(ek);
#pragma unroll
    for (int d = 0; d < 64; ++d) {
      float ekd = __int_as_float(__builtin_amdgcn_readlane(ei, d));
      macc[d] = fmaf(ekd, vv, macc[d]);
    }
  }
  for (int ww = 0; ww < 4; ++ww) {
    if (w == ww) {
      if (ww == 0) {
#pragma unroll
        for (int d = 0; d < 64; ++d) red[d * 65 + lane] = macc[d];
        Sred[lane] = ssum;
      } else {
#pragma unroll
        for (int d = 0; d < 64; ++d) red[d * 65 + lane] += macc[d];
        Sred[lane] += ssum;
      }
    }
    __syncthreads();
  }
  float* Pp = P + (size_t)blockIdx.x * 4096;
#pragma unroll
  for (int e = 0; e < 16; ++e) {
    int idx = t + e * 256;
    Pp[idx] = red[(idx >> 6) * 65 + (idx & 63)];
  }
  if (t < 64) PS[blockIdx.x * 64 + t] = Sred[t];
}

// ---------------------------------------------------------------------------
// Kernel C: kv[bh][d][c] = sum_sp P / sum_sp S[d]
// ---------------------------------------------------------------------------
__global__ __launch_bounds__(256) void ckern(const float* __restrict__ P,
                                             const float* __restrict__ PS,
                                             float* __restrict__ kvb) {
  int bh = blockIdx.x, t = threadIdx.x;
#pragma unroll
  for (int e = 0; e < 16; ++e) {
    int idx = t + e * 256;
    int d = idx >> 6;
    float m = 0.f, s = 0.f;
    for (int sp = 0; sp < 8; ++sp) {
      m += P[(size_t)(bh * 8 + sp) * 4096 + idx];
      s += PS[(bh * 8 + sp) * 64 + d];
    }
    kvb[(size_t)bh * 4096 + idx] = m / s;
  }
}

// ---------------------------------------------------------------------------
// Kernel D1: per 64-row tile, per head: qlog = X@WqT, softmax over kr,
// qkv = softmax(q) @ kv  -- written IN-PLACE over xc rows.
// ---------------------------------------------------------------------------
__global__ __launch_bounds__(256) void d1kern(float* __restrict__ xc,
                                              const float* __restrict__ Wq,
                                              const float* __restrict__ kvb) {
  __shared__ float WqT[64 * 68];
  __shared__ float kvs[64 * 68];
  __shared__ float Xs[64 * 68];
  __shared__ float Et[64 * 68];
  __shared__ float rs[64];
  const int t = threadIdx.x;
  const int tx = t & 15, ty = t >> 4;
  const int row0 = blockIdx.x * 64;
  const int b = row0 >> 14;
  {
    int d4 = (t & 15) * 4;
#pragma unroll
    for (int p = 0; p < 4; ++p) {
      int kr = (t >> 4) + p * 16;
      f4 wq = ldg4(Wq + kr * 64 + d4);
      WqT[(d4 + 0) * 68 + kr] = wq.x; WqT[(d4 + 1) * 68 + kr] = wq.y;
      WqT[(d4 + 2) * 68 + kr] = wq.z; WqT[(d4 + 3) * 68 + kr] = wq.w;
    }
  }
  for (int h = 0; h < 8; ++h) {
    __syncthreads();
#pragma unroll
    for (int p = 0; p < 4; ++p) {
      int lin4 = t + p * 256;
      int d = lin4 >> 4;
      int c = (lin4 & 15) * 4;
      f4 kv = ldg4(kvb + (size_t)(b * 8 + h) * 4096 + lin4 * 4);
      *(f4*)&kvs[d * 68 + c] = kv;
    }
    {
      int d4 = (t & 15) * 4;
#pragma unroll
      for (int p = 0; p < 4; ++p) {
        int r = (t >> 4) + p * 16;
        f4 xv = ldg4(xc + (size_t)(row0 + r) * OCH + h * 64 + d4);
        Xs[(d4 + 0) * 68 + r] = xv.x; Xs[(d4 + 1) * 68 + r] = xv.y;
        Xs[(d4 + 2) * 68 + r] = xv.z; Xs[(d4 + 3) * 68 + r] = xv.w;
      }
    }
    __syncthreads();
    float a1[4][4];
#pragma unroll
    for (int i = 0; i < 4; ++i)
#pragma unroll
      for (int j = 0; j < 4; ++j) a1[i][j] = 0.f;
    const f4* Xs4 = (const f4*)Xs;
    const f4* Wq4 = (const f4*)WqT;
#pragma unroll 8
    for (int k = 0; k < 64; ++k) {
      f4 a = Xs4[k * 17 + ty];
      f4 bq = Wq4[k * 17 + tx];
      float av[4] = {a.x, a.y, a.z, a.w};
      float bv[4] = {bq.x, bq.y, bq.z, bq.w};
#pragma unroll
      for (int i = 0; i < 4; ++i)
#pragma unroll
        for (int j = 0; j < 4; ++j) a1[i][j] = fmaf(av[i], bv[j], a1[i][j]);
    }
#pragma unroll
    for (int i = 0; i < 4; ++i)
#pragma unroll
      for (int j = 0; j < 4; ++j)
        Et[(tx * 4 + j) * 68 + ty * 4 + i] = expf(a1[i][j]);
    __syncthreads();
    if (t < 64) {
      float s = 0.f;
      for (int kr = 0; kr < 64; ++kr) s += Et[kr * 68 + t];
      rs[t] = s;
    }
    __syncthreads();
    float a2[4][4];
#pragma unroll
    for (int i = 0; i < 4; ++i)
#pragma unroll
      for (int j = 0; j < 4; ++j) a2[i][j] = 0.f;
    const f4* Et4 = (const f4*)Et;
    const f4* kv4 = (const f4*)kvs;
#pragma unroll 8
    for (int k = 0; k < 64; ++k) {
      f4 a = Et4[k * 17 + ty];
      f4 bv = kv4[k * 17 + tx];
      float av[4] = {a.x, a.y, a.z, a.w};
      float bb[4] = {bv.x, bv.y, bv.z, bv.w};
#pragma unroll
      for (int i = 0; i < 4; ++i)
#pragma unroll
        for (int j = 0; j < 4; ++j) a2[i][j] = fmaf(av[i], bb[j], a2[i][j]);
    }
#pragma unroll
    for (int i = 0; i < 4; ++i) {
      float inv = 1.0f / rs[ty * 4 + i];
      *(f4*)&xc[(size_t)(row0 + ty * 4 + i) * OCH + h * 64 + tx * 4] =
          make_float4(a2[i][0] * inv, a2[i][1] * inv, a2[i][2] * inv, a2[i][3] * inv);
    }
  }
}

// ---------------------------------------------------------------------------
// Kernel mlp<K,GELU>: Y(row,j) = act(X(row,:) @ W[j,:] + bias[j])
// ---------------------------------------------------------------------------
template <int KTOT, bool DOGELU>
__global__ __launch_bounds__(256) void mlp(const float* __restrict__ X,
                                           const float* __restrict__ W,
                                           const float* __restrict__ bias,
                                           float* __restrict__ Y) {
  __shared__ float Xs[64 * 132];
  __shared__ float Ws[64 * 132];
  const int t = threadIdx.x;
  const int tx = t & 15, ty = t >> 4;
  const int jbase = blockIdx.x * 128;
  const int row0 = blockIdx.y * 128;
  float acc[8][8];
#pragma unroll
  for (int i = 0; i < 8; ++i)
#pragma unroll
    for (int j = 0; j < 8; ++j) acc[i][j] = 0.f;
  const int d4 = (t & 15) * 4;
  for (int kc = 0; kc < KTOT / 64; ++kc) {
    int kb = kc * 64;
    __syncthreads();
#pragma unroll
    for (int p = 0; p < 8; ++p) {
      int r = (t >> 4) + p * 16;
      f4 xv = ldg4(X + (size_t)(row0 + r) * KTOT + kb + d4);
      Xs[(d4 + 0) * 132 + r] = xv.x; Xs[(d4 + 1) * 132 + r] = xv.y;
      Xs[(d4 + 2) * 132 + r] = xv.z; Xs[(d4 + 3) * 132 + r] = xv.w;
    }
#pragma unroll
    for (int p = 0; p < 8; ++p) {
      int jj = (t >> 4) + p * 16;
      f4 wv = ldg4(W + (size_t)(jbase + jj) * KTOT + kb + d4);
      Ws[(d4 + 0) * 132 + jj] = wv.x; Ws[(d4 + 1) * 132 + jj] = wv.y;
      Ws[(d4 + 2) * 132 + jj] = wv.z; Ws[(d4 + 3) * 132 + jj] = wv.w;
    }
    __syncthreads();
    const f4* Xs4 = (const f4*)Xs;
    const f4* Ws4 = (const f4*)Ws;
#pragma unroll 8
    for (int k = 0; k < 64; ++k) {
      f4 a0 = Xs4[k * 33 + ty * 2];
      f4 a1 = Xs4[k * 33 + ty * 2 + 1];
      f4 b0 = Ws4[k * 33 + tx * 2];
      f4 b1 = Ws4[k * 33 + tx * 2 + 1];
      float a[8] = {a0.x, a0.y, a0.z, a0.w, a1.x, a1.y, a1.z, a1.w};
      float b[8] = {b0.x, b0.y, b0.z, b0.w, b1.x, b1.y, b1.z, b1.w};
#pragma unroll
      for (int i = 0; i < 8; ++i)
#pragma unroll
        for (int j = 0; j < 8; ++j) acc[i][j] = fmaf(a[i], b[j], acc[i][j]);
    }
  }
  float bb[8];
#pragma unroll
  for (int j = 0; j < 8; ++j) bb[j] = bias[jbase + tx * 8 + j];
#pragma unroll
  for (int i = 0; i < 8; ++i) {
    int row = row0 + ty * 8 + i;
    float v[8];
#pragma unroll
    for (int j = 0; j < 8; ++j) {
      v[j] = acc[i][j] + bb[j];
      if (DOGELU) v[j] = 0.5f * v[j] * (1.0f + erff(v[j] * 0.70710678118654752440f));
    }
    *(f4*)&Y[(size_t)row * 256 + jbase + tx * 8] = make_float4(v[0], v[1], v[2], v[3]);
    *(f4*)&Y[(size_t)row * 256 + jbase + tx * 8 + 4] = make_float4(v[4], v[5], v[6], v[7]);
  }
}

// ---------------------------------------------------------------------------
extern "C" void kernel_launch(void* const* d_in, const int* in_sizes, int n_in,
                              void* d_out, int out_size, void* d_ws, size_t ws_size,
                              hipStream_t stream) {
  const float* x  = (const float*)d_in[0];
  const float* cw = (const float*)d_in[1];
  const float* cb = (const float*)d_in[2];
  const float* Wq = (const float*)d_in[3];
  const float* Wk = (const float*)d_in[4];
  const float* Wv = (const float*)d_in[5];
  const float* W1 = (const float*)d_in[6];
  const float* b1 = (const float*)d_in[7];
  const float* W2 = (const float*)d_in[8];
  const float* b2 = (const float*)d_in[9];
  float* out = (float*)d_out;
  float* ws = (float*)d_ws;

  // region0 (34,611,200 f32 slots), time-multiplexed:
  //   phase 1 (conv): xp_hi/xp_lo fp16 (8*130*130*256 halfs each)
  //   phase 2 (attn): P (2,097,152) + PS (32,768) + kvb (262,144)
  //   phase 3 (mlp):  y1w (33,554,432)
  _Float16* xph = (_Float16*)ws;
  _Float16* xpl = (_Float16*)(ws + 17305600);
  float* P   = ws;
  float* PS  = ws + 2097152;
  float* kvb = ws + 2129920;
  float* y1w = ws;
  float* xc  = ws + 34611200;              // 67,108,864 f32 (B,N,512)
  _Float16* wh = (_Float16*)(ws + 101720064);  // 1,179,648 halfs
  _Float16* wl = (_Float16*)(ws + 102309888);  // 1,179,648 halfs
  // total: 102,899,712 f32 = 412 MB

  pad_split<<<16900, 256, 0, stream>>>(x, xph, xpl);
  wsplit<<<576, 256, 0, stream>>>(cw, wh, wl);
  conv_mfma<<<dim3(4, 1024), 256, 0, stream>>>(xph, xpl, wh, wl, cb, xc);
  bkern<<<512, 256, 0, stream>>>(xc, Wk, Wv, P, PS);
  ckern<<<64, 256, 0, stream>>>(P, PS, kvb);
  d1kern<<<2048, 256, 0, stream>>>(xc, Wq, kvb);
  mlp<512, true><<<dim3(2, 1024), 256, 0, stream>>>(xc, W1, b1, y1w);
  mlp<256, false><<<dim3(2, 1024), 256, 0, stream>>>(y1w, W2, b2, out);
}